// Round 18
// baseline (432.659 us; speedup 1.0000x reference)
//
#include <hip/hip_runtime.h>
#include <hip/hip_bf16.h>
#include <stdint.h>

#define B_ 32
#define S_ 64
#define E_ 512
#define H_ 1024
#define V_ 32000
#define H3_ 3072
#define NPROD 64    // producer blocks (recurrence)
#define NCONS 192   // consumer blocks (streamed logit GEMM)
#define NGRID (NPROD + NCONS)
#define NPANEL 250  // V / 128
#define NGROUP 8    // one job = 2 batches (M=256 rows) of one panel
#define NJOBS (NPANEL * NGROUP)

typedef __bf16 bf16x8 __attribute__((ext_vector_type(8)));
typedef float f32x4 __attribute__((ext_vector_type(4)));
using bf16 = __hip_bfloat16;

__device__ __forceinline__ unsigned short f2bf(float f) {
  __hip_bfloat16 h = __float2bfloat16(f);
  return __builtin_bit_cast(unsigned short, h);
}
__device__ __forceinline__ float bf2f(unsigned short u) {
  return __bfloat162float(__builtin_bit_cast(__hip_bfloat16, u));
}

__device__ __forceinline__ void async16(void* lds, const void* g) {
  __builtin_amdgcn_global_load_lds(
      (const __attribute__((address_space(1))) unsigned int*)g,
      (__attribute__((address_space(3))) unsigned int*)lds, 16, 0, 0);
}

// MALL-coherent (sc0 sc1) accesses — ONLY for h stores and flags (writers).
// Readers of write-once, gate-protected data use plain cached loads.
__device__ __forceinline__ void st_u32(unsigned* p, unsigned v) {
  __hip_atomic_store(p, v, __ATOMIC_RELAXED, __HIP_MEMORY_SCOPE_AGENT);
}
__device__ __forceinline__ unsigned ld_u32(const unsigned* p) {
  return __hip_atomic_load(p, __ATOMIC_RELAXED, __HIP_MEMORY_SCOPE_AGENT);
}

// fragment-swizzled h layout: element h[b][ig] lives at this bf16 offset
__device__ __forceinline__ int hswz(int b, int ig) {
  return ((((b >> 4) * 32 + (ig >> 5)) * 64) + ((b & 15) + (((ig >> 3) & 3) << 4))) * 8 + (ig & 7);
}

// ---------------- merged feeder kernel (gather_tok + cvt_wihx, one launch) ----------------
__global__ void feed_kernel(const int* __restrict__ toks, const float* __restrict__ emb,
                            bf16* __restrict__ Abf, const float* __restrict__ Wih,
                            bf16* __restrict__ Wx) {
  int bid = blockIdx.x;
  int k = threadIdx.x * 4;
  if (bid < B_ * S_) {
    int b = bid & 31, t = bid >> 5;
    int token = toks[b * S_ + t];
    const float* src = emb + (size_t)token * E_;
    bf16* dst = Abf + (size_t)bid * E_;
    f32x4 v = *(const f32x4*)(src + k);
    dst[k + 0] = __float2bfloat16(v[0]);
    dst[k + 1] = __float2bfloat16(v[1]);
    dst[k + 2] = __float2bfloat16(v[2]);
    dst[k + 3] = __float2bfloat16(v[3]);
  } else {
    int j = bid - B_ * S_;
    f32x4 v = *(const f32x4*)(Wih + (size_t)j * 1024 + k);
    bf16* d = Wx + (size_t)j * 512 + k;
    d[0] = __float2bfloat16(v[0]);
    d[1] = __float2bfloat16(v[1]);
    d[2] = __float2bfloat16(v[2]);
    d[3] = __float2bfloat16(v[3]);
  }
}

// ---------------- merged prep kernel (16.5 KB LDS -> 8 blocks/CU) ----------------
// [0,384): gix GEMM  [384,1152): uv  [1152,1280): h0  [1280,1312): cgate
// [1312,2336): cvt_wb (grid-stride)
__global__ __launch_bounds__(256) void prep_kernel(
    const bf16* __restrict__ Abf, const bf16* __restrict__ Wihx, float* __restrict__ gix,
    const float* __restrict__ img, const float* __restrict__ retr,
    const float* __restrict__ ihW, const float* __restrict__ ihb,
    const float* __restrict__ Wih, const float* __restrict__ gW,
    const float* __restrict__ gb, const float* __restrict__ outW,
    ushort* __restrict__ Wb, float* __restrict__ h32, bf16* __restrict__ hbf0,
    float* __restrict__ u, float* __restrict__ v, float* __restrict__ cg) {
  __shared__ __align__(16) char psm[16640];
  int bid = blockIdx.x, tid = threadIdx.x;

  if (bid < 384) {
    // ---- gix GEMM: [2048,3072] = Abf[2048,512] . Wihx[3072,512]^T ----
    const int nb = 384, mtiles = 16;
    bf16* Ald = (bf16*)psm;
    bf16* Bld = (bf16*)(psm + 8192);
    int swz = (bid & 7) * (nb >> 3) + (bid >> 3);
    int tm = swz % mtiles, tn = swz / mtiles;
    int l = tid & 63, w = tid >> 6;
    const int K = 512, N = H3_;
    const bf16* ga = Abf + (size_t)(tm * 128 + w * 16 + (l >> 2)) * K + (l & 3) * 8;
    const bf16* gbp = Wihx + (size_t)(tn * 128 + w * 16 + (l >> 2)) * K + (l & 3) * 8;
    char* lA = (char*)Ald + w * 1024;
    char* lB = (char*)Bld + w * 1024;
    f32x4 acc[4][4] = {};
    int wm = (w >> 1) * 64, wn = (w & 1) * 64;
    int lr = l & 15, lk = (l >> 4) * 8;
    for (int kt = 0; kt < K; kt += 32) {
      async16(lA, ga);
      async16(lA + 4096, ga + (size_t)64 * K);
      async16(lB, gbp);
      async16(lB + 4096, gbp + (size_t)64 * K);
      ga += 32; gbp += 32;
      __syncthreads();
      bf16x8 af[4], bfv[4];
#pragma unroll
      for (int mi = 0; mi < 4; ++mi) af[mi] = *(const bf16x8*)&Ald[(wm + mi * 16 + lr) * 32 + lk];
#pragma unroll
      for (int ni = 0; ni < 4; ++ni) bfv[ni] = *(const bf16x8*)&Bld[(wn + ni * 16 + lr) * 32 + lk];
#pragma unroll
      for (int mi = 0; mi < 4; ++mi)
#pragma unroll
        for (int ni = 0; ni < 4; ++ni)
          acc[mi][ni] = __builtin_amdgcn_mfma_f32_16x16x32_bf16(af[mi], bfv[ni], acc[mi][ni], 0, 0, 0);
      __syncthreads();
    }
    int cr = (l >> 4) * 4, cc = l & 15;
#pragma unroll
    for (int mi = 0; mi < 4; ++mi)
#pragma unroll
      for (int ni = 0; ni < 4; ++ni) {
        int col = tn * 128 + wn + ni * 16 + cc;
#pragma unroll
        for (int rr = 0; rr < 4; ++rr) {
          int row = tm * 128 + wm + mi * 16 + cr + rr;
          gix[(size_t)row * N + col] = acc[mi][ni][rr];
        }
      }

  } else if (bid < 1152) {
    // ---- uv (no LDS staging; img/retr rows served from L1/L2) ----
    int local = bid - 384;
    bool isU = local < 384;
    const float* src = isU ? img : retr;
    float* dst = isU ? u : v;
    int j0 = (isU ? local : local - 384) * 8;
    int b = tid & 31;
    int j = j0 + (tid >> 5);
    const float* wr = Wih + (size_t)j * 1024 + 512;
    const float* sim = src + (size_t)b * E_;
    float acc = 0.f;
    for (int k = 0; k < E_; k += 4) {
      f32x4 w4 = *(const f32x4*)(wr + k);
      f32x4 s4 = *(const f32x4*)(sim + k);
      acc += w4[0] * s4[0] + w4[1] * s4[1] + w4[2] * s4[2] + w4[3] * s4[3];
    }
    dst[b * H3_ + j] = acc;

  } else if (bid < 1280) {
    // ---- h0 (no LDS staging) ----
    int local = bid - 1152;
    int b = tid & 31, il = tid >> 5;
    int i = local * 8 + il;
    const float* wr = ihW + (size_t)i * E_;
    const float* sim = img + (size_t)b * E_;
    float acc = 0.f;
    for (int k = 0; k < E_; k += 4) {
      f32x4 w4 = *(const f32x4*)(wr + k);
      f32x4 s4 = *(const f32x4*)(sim + k);
      acc += w4[0] * s4[0] + w4[1] * s4[1] + w4[2] * s4[2] + w4[3] * s4[3];
    }
    float hv = tanhf(acc + ihb[i]);
    h32[b * H_ + i] = hv;
    hbf0[hswz(b, i)] = __float2bfloat16(hv);

  } else if (bid < 1312) {
    // ---- cgate ----
    int b = bid - 1280;
    float* red = (float*)psm;
    float acc = 0.f;
    for (int k = tid; k < E_; k += 256)
      acc += img[b * E_ + k] * gW[1024 + k] + retr[b * E_ + k] * gW[1536 + k];
    red[tid] = acc;
    __syncthreads();
    for (int s = 128; s > 0; s >>= 1) {
      if (tid < s) red[tid] += red[tid + s];
      __syncthreads();
    }
    if (tid == 0) cg[b] = red[0] + gb[0];

  } else {
    // ---- cvt_wb: outW fp32 -> bf16 ----
    long n4 = (long)V_ * H_ / 4;
    long stride = 1024L * 256;
    for (long i = (long)(bid - 1312) * 256 + tid; i < n4; i += stride) {
      f32x4 vv = *(const f32x4*)(outW + i * 4);
      ushort4 o;
      o.x = f2bf(vv[0]); o.y = f2bf(vv[1]); o.z = f2bf(vv[2]); o.w = f2bf(vv[3]);
      ((ushort4*)Wb)[i] = o;
    }
  }
}

// ---------------- fence-free producer step sync ----------------
__device__ __forceinline__ void step_sync(unsigned* flags, int bi, unsigned val) {
  __syncthreads();  // per-wave vmcnt(0) before s_barrier drains all stores
  if (threadIdx.x == 0) st_u32(flags + bi * 32, val);
  if (threadIdx.x < NPROD) {
    const unsigned* f = flags + threadIdx.x * 32;
    while (ld_u32(f) < val) __builtin_amdgcn_s_sleep(1);
  }
  __syncthreads();
}

// ---------------- fused persistent kernel (identical to R14/R16) ----------------
__global__ __launch_bounds__(256, 1) void fused_persist(
    const float* __restrict__ Whh, const float* __restrict__ gixAll,
    const float* __restrict__ u, const float* __restrict__ v,
    const float* __restrict__ cg, const float* __restrict__ gW,
    const float* __restrict__ bih, const float* __restrict__ bhh,
    const float* __restrict__ h32init, bf16* __restrict__ hbf,
    unsigned* __restrict__ flags, const bf16* __restrict__ Wb,
    const float* __restrict__ outb, float* __restrict__ out) {
  __shared__ __align__(16) char smem[32768];
  int bi = blockIdx.x;
  int tid = threadIdx.x;

  if (bi < NPROD) {
    // ================= PRODUCER =================
    int w = tid >> 6, l = tid & 63;
    int lr = l & 15, lk8 = (l >> 4) * 8;
    int kbase = w * 256;
    float(*red)[4][2][64][4] = (float(*)[4][2][64][4])smem;

    // preload Whh fragments directly from fp32, split hi/lo in registers
    bf16x8 whi[3][8], wlo[3][8];
#pragma unroll
    for (int g = 0; g < 3; ++g)
#pragma unroll
      for (int ks = 0; ks < 8; ++ks) {
        const float* wp = Whh + (size_t)(g * H_ + bi * 16 + lr) * H_ + kbase + ks * 32 + lk8;
        f32x4 a0 = *(const f32x4*)wp;
        f32x4 a1 = *(const f32x4*)(wp + 4);
        bf16x8 h8, l8;
#pragma unroll
        for (int jj = 0; jj < 4; ++jj) {
          unsigned short hb0 = f2bf(a0[jj]);
          unsigned short hb1 = f2bf(a1[jj]);
          h8[jj] = __builtin_bit_cast(__bf16, hb0);
          h8[jj + 4] = __builtin_bit_cast(__bf16, hb1);
          l8[jj] = __builtin_bit_cast(__bf16, f2bf(a0[jj] - bf2f(hb0)));
          l8[jj + 4] = __builtin_bit_cast(__bf16, f2bf(a1[jj] - bf2f(hb1)));
        }
        whi[g][ks] = h8;
        wlo[g][ks] = l8;
      }
    // gW broadcast B-fragments (alpha dot rides the MFMA pass)
    bf16x8 gwf[8];
#pragma unroll
    for (int ks = 0; ks < 8; ++ks) {
      int kk = (w * 8 + ks) * 32 + (l >> 4) * 8;
      f32x4 g0 = *(const f32x4*)(gW + kk);
      f32x4 g1 = *(const f32x4*)(gW + kk + 4);
      bf16x8 gf;
#pragma unroll
      for (int jj = 0; jj < 4; ++jj) {
        gf[jj] = __builtin_bit_cast(__bf16, f2bf(g0[jj]));
        gf[jj + 4] = __builtin_bit_cast(__bf16, f2bf(g1[jj]));
      }
      gwf[ks] = gf;
    }

    int bq = tid >> 3;
    int il0 = (tid & 7) * 2;
    float uq[2][3], vq[2][3], biq[2][3], bhq[2][3], hold[2];
    float cgq = cg[bq];
#pragma unroll
    for (int q = 0; q < 2; ++q) {
      int ig = bi * 16 + il0 + q;
#pragma unroll
      for (int g = 0; g < 3; ++g) {
        uq[q][g] = u[bq * H3_ + g * H_ + ig];
        vq[q][g] = v[bq * H3_ + g * H_ + ig];
        biq[q][g] = bih[g * H_ + ig];
        bhq[q][g] = bhh[g * H_ + ig];
      }
      hold[q] = h32init[bq * H_ + ig];
    }
    int btq = bq >> 4, breg = bq & 3, lrow = ((bq & 15) >> 2) * 16;

    // prefetch gix for step 0
    float gxn[2][3];
    {
      const float* gx = gixAll + (size_t)bq * H3_;
#pragma unroll
      for (int q = 0; q < 2; ++q) {
        int ig = bi * 16 + il0 + q;
        gxn[q][0] = gx[ig];
        gxn[q][1] = gx[H_ + ig];
        gxn[q][2] = gx[2 * H_ + ig];
      }
    }

    for (int t = 0; t < S_; ++t) {
      // PLAIN cached h loads: 8 producer blocks/XCD share one L2 fill per slot
      const f32x4* hb4 = (const f32x4*)((const char*)hbf + (size_t)t * 65536);
      bf16x8 hh_all[2][8];
#pragma unroll
      for (int bt = 0; bt < 2; ++bt)
#pragma unroll
        for (int ks = 0; ks < 8; ++ks)
          hh_all[bt][ks] = __builtin_bit_cast(bf16x8, hb4[(bt * 32 + w * 8 + ks) * 64 + l]);
      float gxv[2][3];
#pragma unroll
      for (int q = 0; q < 2; ++q) {
        gxv[q][0] = gxn[q][0]; gxv[q][1] = gxn[q][1]; gxv[q][2] = gxn[q][2];
      }
      asm volatile("s_waitcnt vmcnt(0)" ::: "memory");
      __builtin_amdgcn_sched_barrier(0);

      f32x4 acc[4][2] = {};
#pragma unroll
      for (int ks = 0; ks < 8; ++ks) {
#pragma unroll
        for (int bt = 0; bt < 2; ++bt) {
          bf16x8 hh = hh_all[bt][ks];
          acc[0][bt] = __builtin_amdgcn_mfma_f32_16x16x32_bf16(hh, whi[0][ks], acc[0][bt], 0, 0, 0);
          acc[0][bt] = __builtin_amdgcn_mfma_f32_16x16x32_bf16(hh, wlo[0][ks], acc[0][bt], 0, 0, 0);
          acc[1][bt] = __builtin_amdgcn_mfma_f32_16x16x32_bf16(hh, whi[1][ks], acc[1][bt], 0, 0, 0);
          acc[1][bt] = __builtin_amdgcn_mfma_f32_16x16x32_bf16(hh, wlo[1][ks], acc[1][bt], 0, 0, 0);
          acc[2][bt] = __builtin_amdgcn_mfma_f32_16x16x32_bf16(hh, whi[2][ks], acc[2][bt], 0, 0, 0);
          acc[2][bt] = __builtin_amdgcn_mfma_f32_16x16x32_bf16(hh, wlo[2][ks], acc[2][bt], 0, 0, 0);
          acc[3][bt] = __builtin_amdgcn_mfma_f32_16x16x32_bf16(hh, gwf[ks], acc[3][bt], 0, 0, 0);
        }
      }
#pragma unroll
      for (int g = 0; g < 4; ++g)
#pragma unroll
        for (int bt = 0; bt < 2; ++bt)
          *(f32x4*)&red[w][g][bt][l][0] = acc[g][bt];
      __syncthreads();

      int lane0 = lrow + il0;
      float ad = red[0][3][btq][lane0][breg] + red[1][3][btq][lane0][breg] +
                 red[2][3][btq][lane0][breg] + red[3][3][btq][lane0][breg];
      float a = 1.f / (1.f + expf(-(ad + cgq)));
      unsigned short h16[2];
#pragma unroll
      for (int q = 0; q < 2; ++q) {
        int lane = lrow + il0 + q;
        float sr = red[0][0][btq][lane][breg] + red[1][0][btq][lane][breg] +
                   red[2][0][btq][lane][breg] + red[3][0][btq][lane][breg];
        float sz = red[0][1][btq][lane][breg] + red[1][1][btq][lane][breg] +
                   red[2][1][btq][lane][breg] + red[3][1][btq][lane][breg];
        float sn = red[0][2][btq][lane][breg] + red[1][2][btq][lane][breg] +
                   red[2][2][btq][lane][breg] + red[3][2][btq][lane][breg];
        float ir = gxv[q][0] + a * uq[q][0] + (1.f - a) * vq[q][0] + biq[q][0];
        float iz = gxv[q][1] + a * uq[q][1] + (1.f - a) * vq[q][1] + biq[q][1];
        float in_ = gxv[q][2] + a * uq[q][2] + (1.f - a) * vq[q][2] + biq[q][2];
        float r = 1.f / (1.f + expf(-(ir + sr + bhq[q][0])));
        float z = 1.f / (1.f + expf(-(iz + sz + bhq[q][1])));
        float nn = tanhf(in_ + r * (sn + bhq[q][2]));
        float hv = (1.f - z) * nn + z * hold[q];
        hold[q] = hv;
        h16[q] = f2bf(hv);
      }
      {
        unsigned hipack = (unsigned)h16[0] | ((unsigned)h16[1] << 16);
        int off = hswz(bq, bi * 16 + il0);  // even
        unsigned* hi32 = (unsigned*)hbf + (size_t)(t + 1) * 16384;
        st_u32(hi32 + (off >> 1), hipack);  // store stays MALL-coherent
      }
      if (t < S_ - 1) {
        // prefetch gix for step t+1; loads complete during the flag wait
        const float* gx = gixAll + ((size_t)(t + 1) * B_ + bq) * H3_;
#pragma unroll
        for (int q = 0; q < 2; ++q) {
          int ig = bi * 16 + il0 + q;
          gxn[q][0] = gx[ig];
          gxn[q][1] = gx[H_ + ig];
          gxn[q][2] = gx[2 * H_ + ig];
        }
        step_sync(flags, bi, t + 1);
      }
    }
    __syncthreads();
    if (tid == 0) st_u32(flags + bi * 32, S_);

  } else {
    // ================= CONSUMER (M=256 per job; plain cached A-loads) =================
    int c = bi - NPROD;
    int l = tid & 63, w = tid >> 6;
    int wm = (w >> 1) * 64, wn = (w & 1) * 64;
    int lr = l & 15, lk = (l >> 4) * 8;
    bf16* Bld = (bf16*)smem;
    const char* hb_base = (const char*)hbf;

    for (int j = c; j < NJOBS; j += NCONS) {
      int group = j / NPANEL;              // 0..7, covers h slots g*8+1 .. g*8+8
      int panel = j - group * NPANEL;
      int s0 = group * 8 + 1;
      unsigned need = (unsigned)(group * 8 + 8);
      if (w == 0) {                        // wave 0 polls all 64 producer flags
        const unsigned* f = flags + l * 32;
        while (ld_u32(f) < need) __builtin_amdgcn_s_sleep(16);
      }
      __builtin_amdgcn_sched_barrier(0);
      __builtin_amdgcn_s_barrier();
      __builtin_amdgcn_sched_barrier(0);

      const bf16* gb = Wb + (size_t)(panel * 128 + w * 16 + (l >> 2)) * 1024 + (l & 3) * 8;
      f32x4 acc[2][4][4] = {};
      bf16x8 afr[2][2][4];
#pragma unroll
      for (int mt = 0; mt < 2; ++mt)       // pre-issue A(0) for both M-subtiles
#pragma unroll
        for (int mi = 0; mi < 4; ++mi) {
          int r16 = mt * 8 + (wm >> 4) + mi;
          const f32x4* pa = (const f32x4*)(hb_base + (size_t)(s0 + (r16 >> 1)) * 65536 +
                                           (((r16 & 1) * 32 + 0) * 64 + l) * 16);
          afr[0][mt][mi] = __builtin_bit_cast(bf16x8, *pa);
        }
#pragma unroll
      for (int kt = 0; kt < 32; ++kt) {
        char* lB = smem + (kt & 1) * 8192 + w * 1024;
        async16(lB, gb);
        async16(lB + 4096, gb + (size_t)64 * 1024);
        gb += 32;
        if (kt < 31) {
#pragma unroll
          for (int mt = 0; mt < 2; ++mt)
#pragma unroll
            for (int mi = 0; mi < 4; ++mi) {
              int r16 = mt * 8 + (wm >> 4) + mi;
              const f32x4* pa = (const f32x4*)(hb_base + (size_t)(s0 + (r16 >> 1)) * 65536 +
                                               (((r16 & 1) * 32 + (kt + 1)) * 64 + l) * 16);
              afr[(kt + 1) & 1][mt][mi] = __builtin_bit_cast(bf16x8, *pa);
            }
          asm volatile("s_waitcnt vmcnt(8)" ::: "memory");  // B+A_cur done, 8 A_next in flight
        } else {
          asm volatile("s_waitcnt vmcnt(0)" ::: "memory");
        }
        __builtin_amdgcn_sched_barrier(0);
        __builtin_amdgcn_s_barrier();
        __builtin_amdgcn_sched_barrier(0);
        const bf16* Bh = Bld + (kt & 1) * 4096;
        bf16x8 bfv[4];
#pragma unroll
        for (int ni = 0; ni < 4; ++ni)
          bfv[ni] = *(const bf16x8*)&Bh[(wn + ni * 16 + lr) * 32 + lk];
#pragma unroll
        for (int mt = 0; mt < 2; ++mt)
#pragma unroll
          for (int mi = 0; mi < 4; ++mi)
#pragma unroll
            for (int ni = 0; ni < 4; ++ni)
              acc[mt][mi][ni] = __builtin_amdgcn_mfma_f32_16x16x32_bf16(afr[kt & 1][mt][mi], bfv[ni],
                                                                        acc[mt][mi][ni], 0, 0, 0);
      }
      // C write: global row gr (0..255) -> t = group*8 + gr/32, b = gr%32
      int cr = (l >> 4) * 4, cc = l & 15;
#pragma unroll
      for (int mt = 0; mt < 2; ++mt)
#pragma unroll
        for (int mi = 0; mi < 4; ++mi)
#pragma unroll
          for (int ni = 0; ni < 4; ++ni) {
            int col = panel * 128 + wn + ni * 16 + cc;
            float bv = outb[col];
#pragma unroll
            for (int rr = 0; rr < 4; ++rr) {
              int gr = mt * 128 + wm + mi * 16 + cr + rr;
              int t = group * 8 + (gr >> 5);
              int b = gr & 31;
              out[(size_t)(b * S_ + t) * V_ + col] = acc[mt][mi][ni][rr] + bv;
            }
          }
    }
  }
}

// ---------------- launcher ----------------
extern "C" void kernel_launch(void* const* d_in, const int* in_sizes, int n_in, void* d_out,
                              int out_size, void* d_ws, size_t ws_size, hipStream_t stream) {
  const float* img  = (const float*)d_in[0];
  const float* retr = (const float*)d_in[1];
  const int*   toks = (const int*)d_in[2];
  const float* temb = (const float*)d_in[3];
  const float* ihW  = (const float*)d_in[4];
  const float* ihb  = (const float*)d_in[5];
  const float* Wih  = (const float*)d_in[6];
  const float* Whh  = (const float*)d_in[7];
  const float* bih  = (const float*)d_in[8];
  const float* bhh  = (const float*)d_in[9];
  const float* gW   = (const float*)d_in[10];
  const float* gb   = (const float*)d_in[11];
  const float* outW = (const float*)d_in[12];
  const float* outb = (const float*)d_in[13];
  float* out = (float*)d_out;

  char* ws = (char*)d_ws;
  bf16* Wb     = (bf16*)ws;  ws += (size_t)V_ * H_ * 2;
  float* gix   = (float*)ws; ws += (size_t)S_ * B_ * H3_ * 4;
  bf16* Wihx   = (bf16*)ws;  ws += (size_t)H3_ * E_ * 2;
  bf16* Abf    = (bf16*)ws;  ws += (size_t)B_ * S_ * E_ * 2;
  float* u     = (float*)ws; ws += (size_t)B_ * H3_ * 4;
  float* v     = (float*)ws; ws += (size_t)B_ * H3_ * 4;
  float* h32i  = (float*)ws; ws += (size_t)B_ * H_ * 4;
  bf16* hbf    = (bf16*)ws;  ws += (size_t)(S_ + 1) * B_ * H_ * 2;  // 65 h slots, swizzled
  float* cg    = (float*)ws; ws += 128;
  unsigned* flags = (unsigned*)ws; ws += NPROD * 32 * 4;

  // merged feeders for the gix GEMM (one launch)
  feed_kernel<<<B_ * S_ + H3_, 128, 0, stream>>>(toks, temb, Abf, Wih, Wihx);
  (void)hipMemsetAsync(flags, 0, NPROD * 32 * 4, stream);

  // merged prologue: gix GEMM + uv + h0 + cgate + cvt_wb in one launch
  prep_kernel<<<2336, 256, 0, stream>>>(Abf, Wihx, gix, img, retr, ihW, ihb, Wih, gW, gb,
                                        outW, (ushort*)Wb, h32i, hbf, u, v, cg);

  // fused recurrence + streamed logit GEMM (one launch, 256 blocks)
  fused_persist<<<NGRID, 256, 0, stream>>>(Whh, gix, u, v, cg, gW, bih, bhh, h32i,
                                           hbf, flags, Wb, outb, out);
}

// Round 19
// 400.882 us; speedup vs baseline: 1.0793x; 1.0793x over previous
//
#include <hip/hip_runtime.h>
#include <hip/hip_bf16.h>
#include <stdint.h>

#define B_ 32
#define S_ 64
#define E_ 512
#define H_ 1024
#define V_ 32000
#define H3_ 3072
#define NPROD 64    // producer blocks (recurrence)
#define NCONS 192   // consumer blocks (streamed logit GEMM)
#define NGRID (NPROD + NCONS)
#define NPANEL 250  // V / 128
#define NGROUP 8    // one job = 2 batches (M=256 rows) of one panel
#define NJOBS (NPANEL * NGROUP)

typedef __bf16 bf16x8 __attribute__((ext_vector_type(8)));
typedef float f32x4 __attribute__((ext_vector_type(4)));
using bf16 = __hip_bfloat16;

__device__ __forceinline__ unsigned short f2bf(float f) {
  __hip_bfloat16 h = __float2bfloat16(f);
  return __builtin_bit_cast(unsigned short, h);
}
__device__ __forceinline__ float bf2f(unsigned short u) {
  return __bfloat162float(__builtin_bit_cast(__hip_bfloat16, u));
}

__device__ __forceinline__ void async16(void* lds, const void* g) {
  __builtin_amdgcn_global_load_lds(
      (const __attribute__((address_space(1))) unsigned int*)g,
      (__attribute__((address_space(3))) unsigned int*)lds, 16, 0, 0);
}

// MALL-coherent (sc0 sc1) accesses — ONLY for h stores and flags (writers).
// Readers of write-once, gate-protected data use plain cached loads: no L2 can
// hold a pre-write copy (sc0sc1 stores never populate L2; first read is gated;
// replays are deterministic so cross-replay stale == fresh).
__device__ __forceinline__ void st_u32(unsigned* p, unsigned v) {
  __hip_atomic_store(p, v, __ATOMIC_RELAXED, __HIP_MEMORY_SCOPE_AGENT);
}
__device__ __forceinline__ unsigned ld_u32(const unsigned* p) {
  return __hip_atomic_load(p, __ATOMIC_RELAXED, __HIP_MEMORY_SCOPE_AGENT);
}

// fragment-swizzled h layout: element h[b][ig] lives at this bf16 offset
__device__ __forceinline__ int hswz(int b, int ig) {
  return ((((b >> 4) * 32 + (ig >> 5)) * 64) + ((b & 15) + (((ig >> 3) & 3) << 4))) * 8 + (ig & 7);
}

// ---------------- small prologue kernels (feed the gix GEMM) ----------------

__global__ void gather_tok(const int* __restrict__ toks, const float* __restrict__ emb,
                           bf16* __restrict__ Abf) {
  int m = blockIdx.x;
  int b = m & 31, t = m >> 5;
  int token = toks[b * S_ + t];
  const float* src = emb + (size_t)token * E_;
  bf16* dst = Abf + (size_t)m * E_;
  int k = threadIdx.x * 4;
  f32x4 v = *(const f32x4*)(src + k);
  dst[k + 0] = __float2bfloat16(v[0]);
  dst[k + 1] = __float2bfloat16(v[1]);
  dst[k + 2] = __float2bfloat16(v[2]);
  dst[k + 3] = __float2bfloat16(v[3]);
}

__global__ void cvt_wihx(const float* __restrict__ Wih, bf16* __restrict__ Wx) {
  int j = blockIdx.x;
  int k = threadIdx.x * 4;
  f32x4 v = *(const f32x4*)(Wih + (size_t)j * 1024 + k);
  bf16* d = Wx + (size_t)j * 512 + k;
  d[0] = __float2bfloat16(v[0]);
  d[1] = __float2bfloat16(v[1]);
  d[2] = __float2bfloat16(v[2]);
  d[3] = __float2bfloat16(v[3]);
}

// ---------------- merged prep kernel ----------------
// [0,384): gix GEMM  [384,1152): uv  [1152,1280): h0  [1280,1312): cgate
// [1312,2336): cvt_wb (grid-stride)
__global__ __launch_bounds__(256) void prep_kernel(
    const bf16* __restrict__ Abf, const bf16* __restrict__ Wihx, float* __restrict__ gix,
    const float* __restrict__ img, const float* __restrict__ retr,
    const float* __restrict__ ihW, const float* __restrict__ ihb,
    const float* __restrict__ Wih, const float* __restrict__ gW,
    const float* __restrict__ gb, const float* __restrict__ outW,
    ushort* __restrict__ Wb, float* __restrict__ h32, bf16* __restrict__ hbf0,
    float* __restrict__ u, float* __restrict__ v, float* __restrict__ cg) {
  __shared__ __align__(16) char psm[66048];
  int bid = blockIdx.x, tid = threadIdx.x;

  if (bid < 384) {
    // ---- gix GEMM: [2048,3072] = Abf[2048,512] . Wihx[3072,512]^T ----
    const int nb = 384, mtiles = 16;
    bf16* Ald = (bf16*)psm;
    bf16* Bld = (bf16*)(psm + 8192);
    int swz = (bid & 7) * (nb >> 3) + (bid >> 3);
    int tm = swz % mtiles, tn = swz / mtiles;
    int l = tid & 63, w = tid >> 6;
    const int K = 512, N = H3_;
    const bf16* ga = Abf + (size_t)(tm * 128 + w * 16 + (l >> 2)) * K + (l & 3) * 8;
    const bf16* gbp = Wihx + (size_t)(tn * 128 + w * 16 + (l >> 2)) * K + (l & 3) * 8;
    char* lA = (char*)Ald + w * 1024;
    char* lB = (char*)Bld + w * 1024;
    f32x4 acc[4][4] = {};
    int wm = (w >> 1) * 64, wn = (w & 1) * 64;
    int lr = l & 15, lk = (l >> 4) * 8;
    for (int kt = 0; kt < K; kt += 32) {
      async16(lA, ga);
      async16(lA + 4096, ga + (size_t)64 * K);
      async16(lB, gbp);
      async16(lB + 4096, gbp + (size_t)64 * K);
      ga += 32; gbp += 32;
      __syncthreads();
      bf16x8 af[4], bfv[4];
#pragma unroll
      for (int mi = 0; mi < 4; ++mi) af[mi] = *(const bf16x8*)&Ald[(wm + mi * 16 + lr) * 32 + lk];
#pragma unroll
      for (int ni = 0; ni < 4; ++ni) bfv[ni] = *(const bf16x8*)&Bld[(wn + ni * 16 + lr) * 32 + lk];
#pragma unroll
      for (int mi = 0; mi < 4; ++mi)
#pragma unroll
        for (int ni = 0; ni < 4; ++ni)
          acc[mi][ni] = __builtin_amdgcn_mfma_f32_16x16x32_bf16(af[mi], bfv[ni], acc[mi][ni], 0, 0, 0);
      __syncthreads();
    }
    int cr = (l >> 4) * 4, cc = l & 15;
#pragma unroll
    for (int mi = 0; mi < 4; ++mi)
#pragma unroll
      for (int ni = 0; ni < 4; ++ni) {
        int col = tn * 128 + wn + ni * 16 + cc;
#pragma unroll
        for (int rr = 0; rr < 4; ++rr) {
          int row = tm * 128 + wm + mi * 16 + cr + rr;
          gix[(size_t)row * N + col] = acc[mi][ni][rr];
        }
      }

  } else if (bid < 1152) {
    // ---- uv ----
    int local = bid - 384;
    bool isU = local < 384;
    const float* src = isU ? img : retr;
    float* dst = isU ? u : v;
    int j0 = (isU ? local : local - 384) * 8;
    float(*sim)[E_ + 1] = (float(*)[E_ + 1])psm;
    for (int i = tid; i < B_ * E_ / 4; i += 256) {
      f32x4 vv = ((const f32x4*)src)[i];
      int r = (i * 4) / E_, c = (i * 4) % E_;
      sim[r][c + 0] = vv[0]; sim[r][c + 1] = vv[1]; sim[r][c + 2] = vv[2]; sim[r][c + 3] = vv[3];
    }
    __syncthreads();
    int b = tid & 31;
    int j = j0 + (tid >> 5);
    const float* wr = Wih + (size_t)j * 1024 + 512;
    float acc = 0.f;
    for (int k = 0; k < E_; k += 4) {
      f32x4 w4 = *(const f32x4*)(wr + k);
      acc += w4[0] * sim[b][k] + w4[1] * sim[b][k + 1] + w4[2] * sim[b][k + 2] + w4[3] * sim[b][k + 3];
    }
    dst[b * H3_ + j] = acc;

  } else if (bid < 1280) {
    // ---- h0 ----
    int local = bid - 1152;
    float(*sim)[E_ + 1] = (float(*)[E_ + 1])psm;
    for (int i = tid; i < B_ * E_ / 4; i += 256) {
      f32x4 vv = ((const f32x4*)img)[i];
      int r = (i * 4) / E_, c = (i * 4) % E_;
      sim[r][c + 0] = vv[0]; sim[r][c + 1] = vv[1]; sim[r][c + 2] = vv[2]; sim[r][c + 3] = vv[3];
    }
    __syncthreads();
    int b = tid & 31, il = tid >> 5;
    int i = local * 8 + il;
    const float* wr = ihW + (size_t)i * E_;
    float acc = 0.f;
    for (int k = 0; k < E_; k += 4) {
      f32x4 w4 = *(const f32x4*)(wr + k);
      acc += w4[0] * sim[b][k] + w4[1] * sim[b][k + 1] + w4[2] * sim[b][k + 2] + w4[3] * sim[b][k + 3];
    }
    float hv = tanhf(acc + ihb[i]);
    h32[b * H_ + i] = hv;
    hbf0[hswz(b, i)] = __float2bfloat16(hv);

  } else if (bid < 1312) {
    // ---- cgate ----
    int b = bid - 1280;
    float* red = (float*)psm;
    float acc = 0.f;
    for (int k = tid; k < E_; k += 256)
      acc += img[b * E_ + k] * gW[1024 + k] + retr[b * E_ + k] * gW[1536 + k];
    red[tid] = acc;
    __syncthreads();
    for (int s = 128; s > 0; s >>= 1) {
      if (tid < s) red[tid] += red[tid + s];
      __syncthreads();
    }
    if (tid == 0) cg[b] = red[0] + gb[0];

  } else {
    // ---- cvt_wb: outW fp32 -> bf16 ----
    long n4 = (long)V_ * H_ / 4;
    long stride = 1024L * 256;
    for (long i = (long)(bid - 1312) * 256 + tid; i < n4; i += stride) {
      f32x4 vv = *(const f32x4*)(outW + i * 4);
      ushort4 o;
      o.x = f2bf(vv[0]); o.y = f2bf(vv[1]); o.z = f2bf(vv[2]); o.w = f2bf(vv[3]);
      ((ushort4*)Wb)[i] = o;
    }
  }
}

// ---------------- fence-free producer step sync ----------------
__device__ __forceinline__ void step_sync(unsigned* flags, int bi, unsigned val) {
  __syncthreads();  // per-wave vmcnt(0) before s_barrier drains all stores
  if (threadIdx.x == 0) st_u32(flags + bi * 32, val);
  if (threadIdx.x < NPROD) {
    const unsigned* f = flags + threadIdx.x * 32;
    while (ld_u32(f) < val) __builtin_amdgcn_s_sleep(1);
  }
  __syncthreads();
}

// ---------------- fused persistent kernel ----------------
// Blocks 0..63: GRU recurrence (h slot t -> slot t+1, flag = t+1 when done);
//   gix for step t+1 register-prefetched before step_sync; h reads via PLAIN
//   cached loads (write-once slots, gated first touch — see note at st_u32).
// Blocks 64..255: streamed logit GEMM, M=256 jobs, counted-vmcnt pipeline,
//   A-loads also plain cached.
__global__ __launch_bounds__(256, 1) void fused_persist(
    const float* __restrict__ Whh, const float* __restrict__ gixAll,
    const float* __restrict__ u, const float* __restrict__ v,
    const float* __restrict__ cg, const float* __restrict__ gW,
    const float* __restrict__ bih, const float* __restrict__ bhh,
    const float* __restrict__ h32init, bf16* __restrict__ hbf,
    unsigned* __restrict__ flags, const bf16* __restrict__ Wb,
    const float* __restrict__ outb, float* __restrict__ out) {
  __shared__ __align__(16) char smem[32768];
  int bi = blockIdx.x;
  int tid = threadIdx.x;

  if (bi < NPROD) {
    // ================= PRODUCER =================
    int w = tid >> 6, l = tid & 63;
    int lr = l & 15, lk8 = (l >> 4) * 8;
    int kbase = w * 256;
    float(*red)[4][2][64][4] = (float(*)[4][2][64][4])smem;

    // preload Whh fragments directly from fp32, split hi/lo in registers
    bf16x8 whi[3][8], wlo[3][8];
#pragma unroll
    for (int g = 0; g < 3; ++g)
#pragma unroll
      for (int ks = 0; ks < 8; ++ks) {
        const float* wp = Whh + (size_t)(g * H_ + bi * 16 + lr) * H_ + kbase + ks * 32 + lk8;
        f32x4 a0 = *(const f32x4*)wp;
        f32x4 a1 = *(const f32x4*)(wp + 4);
        bf16x8 h8, l8;
#pragma unroll
        for (int jj = 0; jj < 4; ++jj) {
          unsigned short hb0 = f2bf(a0[jj]);
          unsigned short hb1 = f2bf(a1[jj]);
          h8[jj] = __builtin_bit_cast(__bf16, hb0);
          h8[jj + 4] = __builtin_bit_cast(__bf16, hb1);
          l8[jj] = __builtin_bit_cast(__bf16, f2bf(a0[jj] - bf2f(hb0)));
          l8[jj + 4] = __builtin_bit_cast(__bf16, f2bf(a1[jj] - bf2f(hb1)));
        }
        whi[g][ks] = h8;
        wlo[g][ks] = l8;
      }
    // gW broadcast B-fragments (alpha dot rides the MFMA pass)
    bf16x8 gwf[8];
#pragma unroll
    for (int ks = 0; ks < 8; ++ks) {
      int kk = (w * 8 + ks) * 32 + (l >> 4) * 8;
      f32x4 g0 = *(const f32x4*)(gW + kk);
      f32x4 g1 = *(const f32x4*)(gW + kk + 4);
      bf16x8 gf;
#pragma unroll
      for (int jj = 0; jj < 4; ++jj) {
        gf[jj] = __builtin_bit_cast(__bf16, f2bf(g0[jj]));
        gf[jj + 4] = __builtin_bit_cast(__bf16, f2bf(g1[jj]));
      }
      gwf[ks] = gf;
    }

    int bq = tid >> 3;
    int il0 = (tid & 7) * 2;
    float uq[2][3], vq[2][3], biq[2][3], bhq[2][3], hold[2];
    float cgq = cg[bq];
#pragma unroll
    for (int q = 0; q < 2; ++q) {
      int ig = bi * 16 + il0 + q;
#pragma unroll
      for (int g = 0; g < 3; ++g) {
        uq[q][g] = u[bq * H3_ + g * H_ + ig];
        vq[q][g] = v[bq * H3_ + g * H_ + ig];
        biq[q][g] = bih[g * H_ + ig];
        bhq[q][g] = bhh[g * H_ + ig];
      }
      hold[q] = h32init[bq * H_ + ig];
    }
    int btq = bq >> 4, breg = bq & 3, lrow = ((bq & 15) >> 2) * 16;

    // prefetch gix for step 0
    float gxn[2][3];
    {
      const float* gx = gixAll + (size_t)bq * H3_;
#pragma unroll
      for (int q = 0; q < 2; ++q) {
        int ig = bi * 16 + il0 + q;
        gxn[q][0] = gx[ig];
        gxn[q][1] = gx[H_ + ig];
        gxn[q][2] = gx[2 * H_ + ig];
      }
    }

    for (int t = 0; t < S_; ++t) {
      // PLAIN cached h loads: 8 producer blocks/XCD share one L2 fill per slot
      const f32x4* hb4 = (const f32x4*)((const char*)hbf + (size_t)t * 65536);
      bf16x8 hh_all[2][8];
#pragma unroll
      for (int bt = 0; bt < 2; ++bt)
#pragma unroll
        for (int ks = 0; ks < 8; ++ks)
          hh_all[bt][ks] = __builtin_bit_cast(bf16x8, hb4[(bt * 32 + w * 8 + ks) * 64 + l]);
      float gxv[2][3];
#pragma unroll
      for (int q = 0; q < 2; ++q) {
        gxv[q][0] = gxn[q][0]; gxv[q][1] = gxn[q][1]; gxv[q][2] = gxn[q][2];
      }
      asm volatile("s_waitcnt vmcnt(0)" ::: "memory");
      __builtin_amdgcn_sched_barrier(0);

      f32x4 acc[4][2] = {};
#pragma unroll
      for (int ks = 0; ks < 8; ++ks) {
#pragma unroll
        for (int bt = 0; bt < 2; ++bt) {
          bf16x8 hh = hh_all[bt][ks];
          acc[0][bt] = __builtin_amdgcn_mfma_f32_16x16x32_bf16(hh, whi[0][ks], acc[0][bt], 0, 0, 0);
          acc[0][bt] = __builtin_amdgcn_mfma_f32_16x16x32_bf16(hh, wlo[0][ks], acc[0][bt], 0, 0, 0);
          acc[1][bt] = __builtin_amdgcn_mfma_f32_16x16x32_bf16(hh, whi[1][ks], acc[1][bt], 0, 0, 0);
          acc[1][bt] = __builtin_amdgcn_mfma_f32_16x16x32_bf16(hh, wlo[1][ks], acc[1][bt], 0, 0, 0);
          acc[2][bt] = __builtin_amdgcn_mfma_f32_16x16x32_bf16(hh, whi[2][ks], acc[2][bt], 0, 0, 0);
          acc[2][bt] = __builtin_amdgcn_mfma_f32_16x16x32_bf16(hh, wlo[2][ks], acc[2][bt], 0, 0, 0);
          acc[3][bt] = __builtin_amdgcn_mfma_f32_16x16x32_bf16(hh, gwf[ks], acc[3][bt], 0, 0, 0);
        }
      }
#pragma unroll
      for (int g = 0; g < 4; ++g)
#pragma unroll
        for (int bt = 0; bt < 2; ++bt)
          *(f32x4*)&red[w][g][bt][l][0] = acc[g][bt];
      __syncthreads();

      int lane0 = lrow + il0;
      float ad = red[0][3][btq][lane0][breg] + red[1][3][btq][lane0][breg] +
                 red[2][3][btq][lane0][breg] + red[3][3][btq][lane0][breg];
      float a = 1.f / (1.f + expf(-(ad + cgq)));
      unsigned short h16[2];
#pragma unroll
      for (int q = 0; q < 2; ++q) {
        int lane = lrow + il0 + q;
        float sr = red[0][0][btq][lane][breg] + red[1][0][btq][lane][breg] +
                   red[2][0][btq][lane][breg] + red[3][0][btq][lane][breg];
        float sz = red[0][1][btq][lane][breg] + red[1][1][btq][lane][breg] +
                   red[2][1][btq][lane][breg] + red[3][1][btq][lane][breg];
        float sn = red[0][2][btq][lane][breg] + red[1][2][btq][lane][breg] +
                   red[2][2][btq][lane][breg] + red[3][2][btq][lane][breg];
        float ir = gxv[q][0] + a * uq[q][0] + (1.f - a) * vq[q][0] + biq[q][0];
        float iz = gxv[q][1] + a * uq[q][1] + (1.f - a) * vq[q][1] + biq[q][1];
        float in_ = gxv[q][2] + a * uq[q][2] + (1.f - a) * vq[q][2] + biq[q][2];
        float r = 1.f / (1.f + expf(-(ir + sr + bhq[q][0])));
        float z = 1.f / (1.f + expf(-(iz + sz + bhq[q][1])));
        float nn = tanhf(in_ + r * (sn + bhq[q][2]));
        float hv = (1.f - z) * nn + z * hold[q];
        hold[q] = hv;
        h16[q] = f2bf(hv);
      }
      {
        unsigned hipack = (unsigned)h16[0] | ((unsigned)h16[1] << 16);
        int off = hswz(bq, bi * 16 + il0);  // even
        unsigned* hi32 = (unsigned*)hbf + (size_t)(t + 1) * 16384;
        st_u32(hi32 + (off >> 1), hipack);  // store stays MALL-coherent
      }
      if (t < S_ - 1) {
        // prefetch gix for step t+1; loads complete during the flag wait
        const float* gx = gixAll + ((size_t)(t + 1) * B_ + bq) * H3_;
#pragma unroll
        for (int q = 0; q < 2; ++q) {
          int ig = bi * 16 + il0 + q;
          gxn[q][0] = gx[ig];
          gxn[q][1] = gx[H_ + ig];
          gxn[q][2] = gx[2 * H_ + ig];
        }
        step_sync(flags, bi, t + 1);
      }
    }
    __syncthreads();
    if (tid == 0) st_u32(flags + bi * 32, S_);

  } else {
    // ================= CONSUMER (M=256 per job; plain cached A-loads) =================
    int c = bi - NPROD;
    int l = tid & 63, w = tid >> 6;
    int wm = (w >> 1) * 64, wn = (w & 1) * 64;
    int lr = l & 15, lk = (l >> 4) * 8;
    bf16* Bld = (bf16*)smem;
    const char* hb_base = (const char*)hbf;

    for (int j = c; j < NJOBS; j += NCONS) {
      int group = j / NPANEL;              // 0..7, covers h slots g*8+1 .. g*8+8
      int panel = j - group * NPANEL;
      int s0 = group * 8 + 1;
      unsigned need = (unsigned)(group * 8 + 8);
      if (w == 0) {                        // wave 0 polls all 64 producer flags
        const unsigned* f = flags + l * 32;
        while (ld_u32(f) < need) __builtin_amdgcn_s_sleep(16);
      }
      __builtin_amdgcn_sched_barrier(0);
      __builtin_amdgcn_s_barrier();
      __builtin_amdgcn_sched_barrier(0);

      const bf16* gb = Wb + (size_t)(panel * 128 + w * 16 + (l >> 2)) * 1024 + (l & 3) * 8;
      f32x4 acc[2][4][4] = {};
      bf16x8 afr[2][2][4];
#pragma unroll
      for (int mt = 0; mt < 2; ++mt)       // pre-issue A(0) for both M-subtiles
#pragma unroll
        for (int mi = 0; mi < 4; ++mi) {
          int r16 = mt * 8 + (wm >> 4) + mi;
          const f32x4* pa = (const f32x4*)(hb_base + (size_t)(s0 + (r16 >> 1)) * 65536 +
                                           (((r16 & 1) * 32 + 0) * 64 + l) * 16);
          afr[0][mt][mi] = __builtin_bit_cast(bf16x8, *pa);
        }
#pragma unroll
      for (int kt = 0; kt < 32; ++kt) {
        char* lB = smem + (kt & 1) * 8192 + w * 1024;
        async16(lB, gb);
        async16(lB + 4096, gb + (size_t)64 * 1024);
        gb += 32;
        if (kt < 31) {
#pragma unroll
          for (int mt = 0; mt < 2; ++mt)
#pragma unroll
            for (int mi = 0; mi < 4; ++mi) {
              int r16 = mt * 8 + (wm >> 4) + mi;
              const f32x4* pa = (const f32x4*)(hb_base + (size_t)(s0 + (r16 >> 1)) * 65536 +
                                               (((r16 & 1) * 32 + (kt + 1)) * 64 + l) * 16);
              afr[(kt + 1) & 1][mt][mi] = __builtin_bit_cast(bf16x8, *pa);
            }
          asm volatile("s_waitcnt vmcnt(8)" ::: "memory");  // B+A_cur done, 8 A_next in flight
        } else {
          asm volatile("s_waitcnt vmcnt(0)" ::: "memory");
        }
        __builtin_amdgcn_sched_barrier(0);
        __builtin_amdgcn_s_barrier();
        __builtin_amdgcn_sched_barrier(0);
        const bf16* Bh = Bld + (kt & 1) * 4096;
        bf16x8 bfv[4];
#pragma unroll
        for (int ni = 0; ni < 4; ++ni)
          bfv[ni] = *(const bf16x8*)&Bh[(wn + ni * 16 + lr) * 32 + lk];
#pragma unroll
        for (int mt = 0; mt < 2; ++mt)
#pragma unroll
          for (int mi = 0; mi < 4; ++mi)
#pragma unroll
            for (int ni = 0; ni < 4; ++ni)
              acc[mt][mi][ni] = __builtin_amdgcn_mfma_f32_16x16x32_bf16(afr[kt & 1][mt][mi], bfv[ni],
                                                                        acc[mt][mi][ni], 0, 0, 0);
      }
      // C write: global row gr (0..255) -> t = group*8 + gr/32, b = gr%32
      int cr = (l >> 4) * 4, cc = l & 15;
#pragma unroll
      for (int mt = 0; mt < 2; ++mt)
#pragma unroll
        for (int mi = 0; mi < 4; ++mi)
#pragma unroll
          for (int ni = 0; ni < 4; ++ni) {
            int col = panel * 128 + wn + ni * 16 + cc;
            float bv = outb[col];
#pragma unroll
            for (int rr = 0; rr < 4; ++rr) {
              int gr = mt * 128 + wm + mi * 16 + cr + rr;
              int t = group * 8 + (gr >> 5);
              int b = gr & 31;
              out[(size_t)(b * S_ + t) * V_ + col] = acc[mt][mi][ni][rr] + bv;
            }
          }
    }
  }
}

// ---------------- launcher ----------------
extern "C" void kernel_launch(void* const* d_in, const int* in_sizes, int n_in, void* d_out,
                              int out_size, void* d_ws, size_t ws_size, hipStream_t stream) {
  const float* img  = (const float*)d_in[0];
  const float* retr = (const float*)d_in[1];
  const int*   toks = (const int*)d_in[2];
  const float* temb = (const float*)d_in[3];
  const float* ihW  = (const float*)d_in[4];
  const float* ihb  = (const float*)d_in[5];
  const float* Wih  = (const float*)d_in[6];
  const float* Whh  = (const float*)d_in[7];
  const float* bih  = (const float*)d_in[8];
  const float* bhh  = (const float*)d_in[9];
  const float* gW   = (const float*)d_in[10];
  const float* gb   = (const float*)d_in[11];
  const float* outW = (const float*)d_in[12];
  const float* outb = (const float*)d_in[13];
  float* out = (float*)d_out;

  char* ws = (char*)d_ws;
  bf16* Wb     = (bf16*)ws;  ws += (size_t)V_ * H_ * 2;
  float* gix   = (float*)ws; ws += (size_t)S_ * B_ * H3_ * 4;
  bf16* Wihx   = (bf16*)ws;  ws += (size_t)H3_ * E_ * 2;
  bf16* Abf    = (bf16*)ws;  ws += (size_t)B_ * S_ * E_ * 2;
  float* u     = (float*)ws; ws += (size_t)B_ * H3_ * 4;
  float* v     = (float*)ws; ws += (size_t)B_ * H3_ * 4;
  float* h32i  = (float*)ws; ws += (size_t)B_ * H_ * 4;
  bf16* hbf    = (bf16*)ws;  ws += (size_t)(S_ + 1) * B_ * H_ * 2;  // 65 h slots, swizzled
  float* cg    = (float*)ws; ws += 128;
  unsigned* flags = (unsigned*)ws; ws += NPROD * 32 * 4;

  // small feeders for the gix GEMM (must precede prep)
  gather_tok<<<B_ * S_, 128, 0, stream>>>(toks, temb, Abf);
  cvt_wihx<<<H3_, 128, 0, stream>>>(Wih, Wihx);
  (void)hipMemsetAsync(flags, 0, NPROD * 32 * 4, stream);

  // merged prologue: gix GEMM + uv + h0 + cgate + cvt_wb in one launch
  prep_kernel<<<2336, 256, 0, stream>>>(Abf, Wihx, gix, img, retr, ihW, ihb, Wih, gW, gb,
                                        outW, (ushort*)Wb, h32i, hbf, u, v, cg);

  // fused recurrence + streamed logit GEMM (one launch, 256 blocks)
  fused_persist<<<NGRID, 256, 0, stream>>>(Whh, gix, u, v, cg, gW, bih, bhh, h32i,
                                           hbf, flags, Wb, outb, out);
}